// Round 10
// baseline (450.263 us; speedup 1.0000x reference)
//
#include <hip/hip_runtime.h>
#include <math.h>

// Problem constants (B=16, N=M=2048, eps=0.05, 10 sinkhorn iters)
#define NPTS    2048
#define NBATCH  16
#define THREADS 256
#define BLOCKS_PER_BATCH 64     // 1024 blocks = 4/CU x 256 CU exactly
#define ROWS_PER_BLOCK   32
#define ROWS_PER_WAVE    8
#define IPAIRS  1024            // i handled as pairs (k, k+1024)

typedef __attribute__((ext_vector_type(2))) float f2;

static constexpr float KEPS_L  = 28.853900817779268f;   // log2(e)/eps
static constexpr float LOGMU_L = -11.0f;                 // log_mu*log2(e) = -log2(2048), exact
static constexpr float EPS_LN2 = 0.03465735902799727f;   // eps*ln(2)
static constexpr float INV_K2  = 1.2011331562368226e-3f; // 1/KEPS_L^2

// Pack both point clouds as K-scaled float4 {Kx,Ky,Kz,|Kp|^2}.
__global__ void pack_pts(const float* __restrict__ a, const float* __restrict__ b,
                         float4* __restrict__ pa, float4* __restrict__ pb) {
  int idx = blockIdx.x * blockDim.x + threadIdx.x;
  if (idx < NBATCH * NPTS) {
    float x = KEPS_L * a[3*idx], y = KEPS_L * a[3*idx+1], z = KEPS_L * a[3*idx+2];
    pa[idx] = make_float4(x, y, z, fmaf(x, x, fmaf(y, y, z*z)));
    float u = KEPS_L * b[3*idx], v = KEPS_L * b[3*idx+1], w = KEPS_L * b[3*idx+2];
    pb[idx] = make_float4(u, v, w, fmaf(u, u, fmaf(v, v, w*w)));
  }
}

// One half-iteration of log-domain Sinkhorn (exp2-domain, per-batch shift A).
// Model (fit r4-r9): issue-bound on total vector-instruction count (~4 cyc/
// inst, pipe-independent). This version minimizes inst/pair by packing the
// f2 axis over i-PAIRS (k, k+1024) with an SoA-f2 LDS layout:
//   sxx/syy/szz[k] = {Kx_k, Kx_{k+1024}}..., sww = -0.5|Kp|^2 pairs,
//   swt = weight pairs 2^(a_i-A).  (5 x 8KB = 40960 B exactly.)
// Q-side constants splat ONCE before the loop (32 f2 regs). Inner body per
// i-step (1024 pairs): 5 ds_read_b64 + 8 x (4 pk_fma + 2 sqrt + 2 exp2 +
// 1 pk_fma). No clamp (min scaled d2 ~0.02 >> fp error), no index math
// (imm offsets).
template<bool INIT, bool CHAMFER>
__global__ __launch_bounds__(THREADS, 4)
void lse_pass(const float4* __restrict__ pR, const float4* __restrict__ pQ,
              const float* __restrict__ dualR, float* __restrict__ dualQ,
              float* __restrict__ chamPart) {
  __shared__ f2 sxx[IPAIRS];
  __shared__ f2 syy[IPAIRS];
  __shared__ f2 szz[IPAIRS];
  __shared__ f2 sww[IPAIRS];   // {-0.5|Kp|^2 lo, hi}
  __shared__ f2 swt[IPAIRS];   // {w lo, w hi}
  // total 40960 B exactly -> 4 blocks/CU; sxx doubles as reduce scratch.

  const int b    = blockIdx.x >> 6;        // batch
  const int blk  = blockIdx.x & 63;        // block within batch
  const int tid  = threadIdx.x;
  const int lane = tid & 63;
  const int wave = tid >> 6;

  const float4* __restrict__ px = pR + b * NPTS;
  float A;

  if constexpr (INIT) {
    // f == 0: a_i = LOGMU_L for all i -> A = LOGMU_L, w_i = 1
#pragma unroll
    for (int u = 0; u < 4; ++u) {
      int k = tid + u * THREADS;
      float4 a4 = px[k];
      float4 b4 = px[k + IPAIRS];
      sxx[k] = (f2){a4.x, b4.x};
      syy[k] = (f2){a4.y, b4.y};
      szz[k] = (f2){a4.z, b4.z};
      sww[k] = (f2){-0.5f * a4.w, -0.5f * b4.w};
      swt[k] = (f2){1.f, 1.f};
    }
    A = LOGMU_L;
    __syncthreads();
  } else {
    const float* __restrict__ fb = dualR + b * NPTS;
    float av[8];
    float lm = -3.4e38f;
#pragma unroll
    for (int u = 0; u < 8; ++u) {
      int k = tid + u * THREADS;
      float a = fmaf(fb[k], KEPS_L, LOGMU_L);
      av[u] = a;
      lm = fmaxf(lm, a);
    }
#pragma unroll
    for (int off = 32; off; off >>= 1) lm = fmaxf(lm, __shfl_xor(lm, off));
    float* scratch = (float*)sxx;          // sxx not yet staged -> usable
    if (lane == 0) scratch[wave] = lm;
    __syncthreads();
    A = fmaxf(fmaxf(scratch[0], scratch[1]), fmaxf(scratch[2], scratch[3]));
    __syncthreads();                       // done reading scratch before staging
#pragma unroll
    for (int u = 0; u < 4; ++u) {
      int k = tid + u * THREADS;           // 0..1023; partner k+1024 -> av[u+4]
      float4 a4 = px[k];
      float4 b4 = px[k + IPAIRS];
      sxx[k] = (f2){a4.x, b4.x};
      syy[k] = (f2){a4.y, b4.y};
      szz[k] = (f2){a4.z, b4.z};
      sww[k] = (f2){-0.5f * a4.w, -0.5f * b4.w};
      swt[k] = (f2){__builtin_amdgcn_exp2f(av[u] - A),
                    __builtin_amdgcn_exp2f(av[u + 4] - A)};
    }
    __syncthreads();
  }

  const float4* __restrict__ qa = pQ + b * NPTS;
  float* __restrict__ gout = dualQ + b * NPTS;
  const int j0 = blk * ROWS_PER_BLOCK + wave * ROWS_PER_WAVE;

  // Q-side splats hoisted out of the loop (loop-invariant f2 constants)
  f2 qxx[8], qyy[8], qzz[8], qww[8], s2[8], m2[8];
#pragma unroll
  for (int r = 0; r < ROWS_PER_WAVE; ++r) {
    float4 q = qa[j0 + r];
    qxx[r] = (f2){q.x, q.x};
    qyy[r] = (f2){q.y, q.y};
    qzz[r] = (f2){q.z, q.z};
    qww[r] = (f2){q.w, q.w};
    s2[r] = (f2){0.f, 0.f};
    if constexpr (CHAMFER) m2[r] = (f2){3.4e38f, 3.4e38f};
  }

  const f2 kM2 = (f2){-2.f, -2.f};

#pragma unroll 4
  for (int it = 0; it < IPAIRS / 64; ++it) {
    const int k = it * 64 + lane;
    const f2 pxx = sxx[k];
    const f2 pyy = syy[k];
    const f2 pzz = szz[k];
    const f2 pww = sww[k];
    const f2 wt  = swt[k];
#pragma unroll
    for (int r = 0; r < ROWS_PER_WAVE; ++r) {
      f2 t  = __builtin_elementwise_fma(pxx, qxx[r],
              __builtin_elementwise_fma(pyy, qyy[r],
              __builtin_elementwise_fma(pzz, qzz[r], pww)));
      f2 d2 = __builtin_elementwise_fma(kM2, t, qww[r]);   // = K^2*dist^2 > 0
      if constexpr (CHAMFER) m2[r] = __builtin_elementwise_min(m2[r], d2);
      f2 e;
      e.x = __builtin_amdgcn_exp2f(-__builtin_amdgcn_sqrtf(d2.x));
      e.y = __builtin_amdgcn_exp2f(-__builtin_amdgcn_sqrtf(d2.y));
      s2[r] = __builtin_elementwise_fma(e, wt, s2[r]);
    }
  }

  float s[ROWS_PER_WAVE], m[ROWS_PER_WAVE];
#pragma unroll
  for (int r = 0; r < ROWS_PER_WAVE; ++r) {
    s[r] = s2[r].x + s2[r].y;
    if constexpr (CHAMFER) m[r] = fminf(m2[r].x, m2[r].y);
  }

  // full-wave xor reductions (all lanes end with the result)
#pragma unroll
  for (int off = 32; off; off >>= 1) {
#pragma unroll
    for (int r = 0; r < ROWS_PER_WAVE; ++r) {
      s[r] += __shfl_xor(s[r], off);
      if constexpr (CHAMFER) m[r] = fminf(m[r], __shfl_xor(m[r], off));
    }
  }

  if (lane == 0) {
#pragma unroll
    for (int r = 0; r < ROWS_PER_WAVE; ++r)
      gout[j0 + r] = -EPS_LN2 * (A + __builtin_amdgcn_logf(fmaxf(s[r], 1e-37f)));
  }

  if constexpr (CHAMFER) {
    float chamAcc = 0.f;
#pragma unroll
    for (int r = 0; r < ROWS_PER_WAVE; ++r) chamAcc += m[r];
    chamAcc *= INV_K2;                      // back to unscaled d2
    __syncthreads();                        // everyone done with LDS arrays
    float* scratch = (float*)sxx;
    if (lane == 0) scratch[wave] = chamAcc;
    __syncthreads();
    if (tid == 0)
      chamPart[blockIdx.x] = (scratch[0] + scratch[1]) + (scratch[2] + scratch[3]);
  }
}

// Stage 1: 66 blocks x 256 threads, one float4 per thread (66*256*4 = 67584
// floats = f(32768) + g(32768) + cham(2048), contiguous). Deterministic.
__global__ void final1(const float4* __restrict__ base, float* __restrict__ part) {
  __shared__ float red[4];
  const int idx = blockIdx.x * 256 + threadIdx.x;
  float4 v = base[idx];
  float acc = (v.x + v.y) + (v.z + v.w);
#pragma unroll
  for (int off = 32; off; off >>= 1) acc += __shfl_xor(acc, off);
  const int lane = threadIdx.x & 63, wave = threadIdx.x >> 6;
  if (lane == 0) red[wave] = acc;
  __syncthreads();
  if (threadIdx.x == 0) part[blockIdx.x] = (red[0] + red[1]) + (red[2] + red[3]);
}

// Stage 2: one wave sums the 66 partials.
__global__ void final2(const float* __restrict__ part, float* __restrict__ out) {
  const int lane = threadIdx.x;
  float acc = part[lane];                       // 66 entries, lanes 0..63
  if (lane < 2) acc += part[lane + 64];
#pragma unroll
  for (int off = 32; off; off >>= 1) acc += __shfl_xor(acc, off);
  if (lane == 0) out[0] = acc;
}

extern "C" void kernel_launch(void* const* d_in, const int* in_sizes, int n_in,
                              void* d_out, int out_size, void* d_ws, size_t ws_size,
                              hipStream_t stream) {
  const float* outPts = (const float*)d_in[0];
  const float* tgtPts = (const float*)d_in[1];
  float* out = (float*)d_out;

  char* ws = (char*)d_ws;
  float4* pwA = (float4*)ws;                                  // 32768 * 16 B
  float4* pwB = (float4*)(ws + (size_t)NBATCH * NPTS * 16);   // 32768 * 16 B
  float*  f   = (float*)(ws + (size_t)2 * NBATCH * NPTS * 16);// 32768 floats
  float*  g   = f + NBATCH * NPTS;                            // 32768 floats
  float*  cham = g + NBATCH * NPTS;                           // 2048 floats
  float*  part = cham + 2048;                                 // 66 floats
  // total ws use: ~1.26 MB

  pack_pts<<<dim3(128), dim3(256), 0, stream>>>(outPts, tgtPts, pwA, pwB);

  const dim3 grid(NBATCH * BLOCKS_PER_BATCH);  // 1024 blocks x 256 threads
  const dim3 blk(THREADS);

  // iteration 1: f==0 (INIT), fuse both chamfer directions
  lse_pass<true,  true ><<<grid, blk, 0, stream>>>(pwA, pwB, nullptr, g, cham);
  lse_pass<false, true ><<<grid, blk, 0, stream>>>(pwB, pwA, g, f, cham + 1024);
  // iterations 2..10
  for (int t = 1; t < 10; ++t) {
    lse_pass<false, false><<<grid, blk, 0, stream>>>(pwA, pwB, f, g, nullptr);
    lse_pass<false, false><<<grid, blk, 0, stream>>>(pwB, pwA, g, f, nullptr);
  }

  // emd_loss = sum(f) + sum(g) (N==M), plus chamfer partials; contiguous from f.
  final1<<<dim3(66), dim3(256), 0, stream>>>((const float4*)f, part);
  final2<<<dim3(1), dim3(64), 0, stream>>>(part, out);
}

// Round 11
// 363.272 us; speedup vs baseline: 1.2395x; 1.2395x over previous
//
#include <hip/hip_runtime.h>
#include <math.h>

// Problem constants (B=16, N=M=2048, eps=0.05, 10 sinkhorn iters)
#define NPTS    2048
#define NBATCH  16
#define THREADS 256
#define BLOCKS_PER_BATCH 64     // 1024 blocks = 4/CU x 256 CU exactly
#define ROWS_PER_BLOCK   32
#define ROWS_PER_WAVE    8
#define IPAIRS  1024            // i handled as pairs (k, k+1024)

typedef __attribute__((ext_vector_type(2))) float f2;

static constexpr float KEPS_L  = 28.853900817779268f;   // log2(e)/eps
static constexpr float LOGMU_L = -11.0f;                 // log_mu*log2(e) = -log2(2048), exact
static constexpr float EPS_LN2 = 0.03465735902799727f;   // eps*ln(2)
static constexpr float INV_K2  = 1.2011331562368226e-3f; // 1/KEPS_L^2

// Pack both point clouds as K-scaled float4 {Kx,Ky,Kz,|Kp|^2}.
__global__ void pack_pts(const float* __restrict__ a, const float* __restrict__ b,
                         float4* __restrict__ pa, float4* __restrict__ pb) {
  int idx = blockIdx.x * blockDim.x + threadIdx.x;
  if (idx < NBATCH * NPTS) {
    float x = KEPS_L * a[3*idx], y = KEPS_L * a[3*idx+1], z = KEPS_L * a[3*idx+2];
    pa[idx] = make_float4(x, y, z, fmaf(x, x, fmaf(y, y, z*z)));
    float u = KEPS_L * b[3*idx], v = KEPS_L * b[3*idx+1], w = KEPS_L * b[3*idx+2];
    pb[idx] = make_float4(u, v, w, fmaf(u, u, fmaf(v, v, w*w)));
  }
}

// One half-iteration of log-domain Sinkhorn (exp2-domain, per-batch shift A).
// Round-10 lesson: this structure needs ~110-130 VGPRs; __launch_bounds__'
// second arg forced a 64-VGPR allocation -> 250 MB/dispatch scratch spills
// (FETCH 114 MB, WRITE 136 MB, VALUBusy 18%). Fix: NO min-occupancy bound
// (VGPR cap 256, compiler allocates what it needs, zero spills). LDS
// (40960 B) still limits residency to 4 blocks/CU; r9 showed occupancy
// sensitivity is weak, so 3-4 blocks/CU is fine.
// SoA-f2 LDS layout over i-PAIRS (k, k+1024): q-side splats hoisted (32 f2),
// inner body per i-step (1024 pairs): 5 ds_read_b64 + 8 x (4 pk_fma +
// 2 sqrt + 2 exp2 + 1 pk_fma). No clamp (min scaled d2 >> fp error), no
// index math (imm offsets).
template<bool INIT, bool CHAMFER>
__global__ __launch_bounds__(THREADS)
void lse_pass(const float4* __restrict__ pR, const float4* __restrict__ pQ,
              const float* __restrict__ dualR, float* __restrict__ dualQ,
              float* __restrict__ chamPart) {
  __shared__ f2 sxx[IPAIRS];
  __shared__ f2 syy[IPAIRS];
  __shared__ f2 szz[IPAIRS];
  __shared__ f2 sww[IPAIRS];   // {-0.5|Kp|^2 lo, hi}
  __shared__ f2 swt[IPAIRS];   // {w lo, w hi}
  // total 40960 B exactly -> 4 blocks/CU; sxx doubles as reduce scratch.

  const int b    = blockIdx.x >> 6;        // batch
  const int blk  = blockIdx.x & 63;        // block within batch
  const int tid  = threadIdx.x;
  const int lane = tid & 63;
  const int wave = tid >> 6;

  const float4* __restrict__ px = pR + b * NPTS;
  float A;

  if constexpr (INIT) {
    // f == 0: a_i = LOGMU_L for all i -> A = LOGMU_L, w_i = 1
#pragma unroll
    for (int u = 0; u < 4; ++u) {
      int k = tid + u * THREADS;
      float4 a4 = px[k];
      float4 b4 = px[k + IPAIRS];
      sxx[k] = (f2){a4.x, b4.x};
      syy[k] = (f2){a4.y, b4.y};
      szz[k] = (f2){a4.z, b4.z};
      sww[k] = (f2){-0.5f * a4.w, -0.5f * b4.w};
      swt[k] = (f2){1.f, 1.f};
    }
    A = LOGMU_L;
    __syncthreads();
  } else {
    const float* __restrict__ fb = dualR + b * NPTS;
    float av[8];
    float lm = -3.4e38f;
#pragma unroll
    for (int u = 0; u < 8; ++u) {
      int k = tid + u * THREADS;
      float a = fmaf(fb[k], KEPS_L, LOGMU_L);
      av[u] = a;
      lm = fmaxf(lm, a);
    }
#pragma unroll
    for (int off = 32; off; off >>= 1) lm = fmaxf(lm, __shfl_xor(lm, off));
    float* scratch = (float*)sxx;          // sxx not yet staged -> usable
    if (lane == 0) scratch[wave] = lm;
    __syncthreads();
    A = fmaxf(fmaxf(scratch[0], scratch[1]), fmaxf(scratch[2], scratch[3]));
    __syncthreads();                       // done reading scratch before staging
#pragma unroll
    for (int u = 0; u < 4; ++u) {
      int k = tid + u * THREADS;           // 0..1023; partner k+1024 -> av[u+4]
      float4 a4 = px[k];
      float4 b4 = px[k + IPAIRS];
      sxx[k] = (f2){a4.x, b4.x};
      syy[k] = (f2){a4.y, b4.y};
      szz[k] = (f2){a4.z, b4.z};
      sww[k] = (f2){-0.5f * a4.w, -0.5f * b4.w};
      swt[k] = (f2){__builtin_amdgcn_exp2f(av[u] - A),
                    __builtin_amdgcn_exp2f(av[u + 4] - A)};
    }
    __syncthreads();
  }

  const float4* __restrict__ qa = pQ + b * NPTS;
  float* __restrict__ gout = dualQ + b * NPTS;
  const int j0 = blk * ROWS_PER_BLOCK + wave * ROWS_PER_WAVE;

  // Q-side splats hoisted out of the loop (loop-invariant f2 constants)
  f2 qxx[8], qyy[8], qzz[8], qww[8], s2[8], m2[8];
#pragma unroll
  for (int r = 0; r < ROWS_PER_WAVE; ++r) {
    float4 q = qa[j0 + r];
    qxx[r] = (f2){q.x, q.x};
    qyy[r] = (f2){q.y, q.y};
    qzz[r] = (f2){q.z, q.z};
    qww[r] = (f2){q.w, q.w};
    s2[r] = (f2){0.f, 0.f};
    if constexpr (CHAMFER) m2[r] = (f2){3.4e38f, 3.4e38f};
  }

  const f2 kM2 = (f2){-2.f, -2.f};

#pragma unroll 2
  for (int it = 0; it < IPAIRS / 64; ++it) {
    const int k = it * 64 + lane;
    const f2 pxx = sxx[k];
    const f2 pyy = syy[k];
    const f2 pzz = szz[k];
    const f2 pww = sww[k];
    const f2 wt  = swt[k];
#pragma unroll
    for (int r = 0; r < ROWS_PER_WAVE; ++r) {
      f2 t  = __builtin_elementwise_fma(pxx, qxx[r],
              __builtin_elementwise_fma(pyy, qyy[r],
              __builtin_elementwise_fma(pzz, qzz[r], pww)));
      f2 d2 = __builtin_elementwise_fma(kM2, t, qww[r]);   // = K^2*dist^2 > 0
      if constexpr (CHAMFER) m2[r] = __builtin_elementwise_min(m2[r], d2);
      f2 e;
      e.x = __builtin_amdgcn_exp2f(-__builtin_amdgcn_sqrtf(d2.x));
      e.y = __builtin_amdgcn_exp2f(-__builtin_amdgcn_sqrtf(d2.y));
      s2[r] = __builtin_elementwise_fma(e, wt, s2[r]);
    }
  }

  float s[ROWS_PER_WAVE], m[ROWS_PER_WAVE];
#pragma unroll
  for (int r = 0; r < ROWS_PER_WAVE; ++r) {
    s[r] = s2[r].x + s2[r].y;
    if constexpr (CHAMFER) m[r] = fminf(m2[r].x, m2[r].y);
  }

  // full-wave xor reductions (all lanes end with the result)
#pragma unroll
  for (int off = 32; off; off >>= 1) {
#pragma unroll
    for (int r = 0; r < ROWS_PER_WAVE; ++r) {
      s[r] += __shfl_xor(s[r], off);
      if constexpr (CHAMFER) m[r] = fminf(m[r], __shfl_xor(m[r], off));
    }
  }

  if (lane == 0) {
#pragma unroll
    for (int r = 0; r < ROWS_PER_WAVE; ++r)
      gout[j0 + r] = -EPS_LN2 * (A + __builtin_amdgcn_logf(fmaxf(s[r], 1e-37f)));
  }

  if constexpr (CHAMFER) {
    float chamAcc = 0.f;
#pragma unroll
    for (int r = 0; r < ROWS_PER_WAVE; ++r) chamAcc += m[r];
    chamAcc *= INV_K2;                      // back to unscaled d2
    __syncthreads();                        // everyone done with LDS arrays
    float* scratch = (float*)sxx;
    if (lane == 0) scratch[wave] = chamAcc;
    __syncthreads();
    if (tid == 0)
      chamPart[blockIdx.x] = (scratch[0] + scratch[1]) + (scratch[2] + scratch[3]);
  }
}

// Stage 1: 66 blocks x 256 threads, one float4 per thread (66*256*4 = 67584
// floats = f(32768) + g(32768) + cham(2048), contiguous). Deterministic.
__global__ void final1(const float4* __restrict__ base, float* __restrict__ part) {
  __shared__ float red[4];
  const int idx = blockIdx.x * 256 + threadIdx.x;
  float4 v = base[idx];
  float acc = (v.x + v.y) + (v.z + v.w);
#pragma unroll
  for (int off = 32; off; off >>= 1) acc += __shfl_xor(acc, off);
  const int lane = threadIdx.x & 63, wave = threadIdx.x >> 6;
  if (lane == 0) red[wave] = acc;
  __syncthreads();
  if (threadIdx.x == 0) part[blockIdx.x] = (red[0] + red[1]) + (red[2] + red[3]);
}

// Stage 2: one wave sums the 66 partials.
__global__ void final2(const float* __restrict__ part, float* __restrict__ out) {
  const int lane = threadIdx.x;
  float acc = part[lane];                       // 66 entries, lanes 0..63
  if (lane < 2) acc += part[lane + 64];
#pragma unroll
  for (int off = 32; off; off >>= 1) acc += __shfl_xor(acc, off);
  if (lane == 0) out[0] = acc;
}

extern "C" void kernel_launch(void* const* d_in, const int* in_sizes, int n_in,
                              void* d_out, int out_size, void* d_ws, size_t ws_size,
                              hipStream_t stream) {
  const float* outPts = (const float*)d_in[0];
  const float* tgtPts = (const float*)d_in[1];
  float* out = (float*)d_out;

  char* ws = (char*)d_ws;
  float4* pwA = (float4*)ws;                                  // 32768 * 16 B
  float4* pwB = (float4*)(ws + (size_t)NBATCH * NPTS * 16);   // 32768 * 16 B
  float*  f   = (float*)(ws + (size_t)2 * NBATCH * NPTS * 16);// 32768 floats
  float*  g   = f + NBATCH * NPTS;                            // 32768 floats
  float*  cham = g + NBATCH * NPTS;                           // 2048 floats
  float*  part = cham + 2048;                                 // 66 floats
  // total ws use: ~1.26 MB

  pack_pts<<<dim3(128), dim3(256), 0, stream>>>(outPts, tgtPts, pwA, pwB);

  const dim3 grid(NBATCH * BLOCKS_PER_BATCH);  // 1024 blocks x 256 threads
  const dim3 blk(THREADS);

  // iteration 1: f==0 (INIT), fuse both chamfer directions
  lse_pass<true,  true ><<<grid, blk, 0, stream>>>(pwA, pwB, nullptr, g, cham);
  lse_pass<false, true ><<<grid, blk, 0, stream>>>(pwB, pwA, g, f, cham + 1024);
  // iterations 2..10
  for (int t = 1; t < 10; ++t) {
    lse_pass<false, false><<<grid, blk, 0, stream>>>(pwA, pwB, f, g, nullptr);
    lse_pass<false, false><<<grid, blk, 0, stream>>>(pwB, pwA, g, f, nullptr);
  }

  // emd_loss = sum(f) + sum(g) (N==M), plus chamfer partials; contiguous from f.
  final1<<<dim3(66), dim3(256), 0, stream>>>((const float4*)f, part);
  final2<<<dim3(1), dim3(64), 0, stream>>>(part, out);
}